// Round 8
// baseline (89.173 us; speedup 1.0000x reference)
//
#include <hip/hip_runtime.h>
#include <math.h>

#define B_ 4096
#define T_ 64
#define E_ 256
#define H_ 64
#define V_ 32000
#define THREADS 1024

typedef __attribute__((ext_vector_type(8))) short bf16x8;
typedef __attribute__((ext_vector_type(4))) float f32x4;
typedef __attribute__((ext_vector_type(4))) unsigned int u32x4;

__device__ __forceinline__ short f2bf(float x) {
    unsigned u = __float_as_uint(x);
    return (short)((u + 0x7FFFu + ((u >> 16) & 1u)) >> 16);
}
__device__ __forceinline__ unsigned cvt_pk_bf16(float lo, float hi) {
    unsigned r;
    asm("v_cvt_pk_bf16_f32 %0, %1, %2" : "=v"(r) : "v"(lo), "v"(hi));
    return r;
}
__device__ __forceinline__ float sigm(float x) { return 1.0f / (1.0f + __expf(-x)); }
__device__ __forceinline__ float tanh_(float x) { return 1.0f - 2.0f / (1.0f + __expf(2.0f * x)); }

__device__ __forceinline__ void gld16(const void* g, void* l) {
    __builtin_amdgcn_global_load_lds(
        (const __attribute__((address_space(1))) void*)g,
        (__attribute__((address_space(3))) void*)l, 16, 0, 0);
}

// ---------------------------------------------------------------------------
// Prep (wih_frag layout identical to R4-R7, verified):
//  wih_frag[((vv*2+tl)*8 + kc)*512 + lane*8 + jj]:
//    gate g = tl*128 + (lane&1)*64 + vv*8 + ((lane&15)>>1)
//    k      = kc*32 + (lane>>4)*8 + jj
//  whh_g: bf16 [g][k] row-major;  bias_f = b_ih + b_hh
//  emb_bf (optional, tabN>0): whole embedding table converted to bf16 (RNE via
//  v_cvt_pk_bf16_f32) so the main kernel can stage via global_load_lds.
// ---------------------------------------------------------------------------
__global__ void prep_kernel(const float* __restrict__ W_ih,
                            const float* __restrict__ W_hh,
                            const float* __restrict__ b_ih,
                            const float* __restrict__ b_hh,
                            const float* __restrict__ emb_table,
                            short* __restrict__ wih_frag,
                            short* __restrict__ whh_g,
                            float* __restrict__ bias_f,
                            short* __restrict__ emb_bf,
                            int tabN) {
    int tid = blockIdx.x * blockDim.x + threadIdx.x;
    int stride = gridDim.x * blockDim.x;
    for (int i = tid; i < 65536; i += stride) {
        int jj = i & 7;
        int l  = (i >> 3) & 63;
        int kc = (i >> 9) & 7;
        int tl = (i >> 12) & 1;
        int vv = i >> 13;
        int uu = (l & 15) >> 1, pp = l & 1;
        int g = tl * 128 + pp * 64 + vv * 8 + uu;
        int k = kc * 32 + (l >> 4) * 8 + jj;
        wih_frag[i] = f2bf(W_ih[g * E_ + k]);
    }
    for (int i = tid; i < 256 * 64; i += stride) whh_g[i] = f2bf(W_hh[i]);
    for (int i = tid; i < 256; i += stride) bias_f[i] = b_ih[i] + b_hh[i];
    // vectorized table conversion (float4 -> 2x cvt_pk -> 8B store)
    for (int i = tid; i < (tabN >> 2); i += stride) {
        float4 v = ((const float4*)emb_table)[i];
        uint2 w;
        w.x = cvt_pk_bf16(v.x, v.y);
        w.y = cvt_pk_bf16(v.z, v.w);
        ((uint2*)emb_bf)[i] = w;
    }
}

// ---------------------------------------------------------------------------
// Producer/consumer MFMA LSTM. grid 256 (1 block/CU), 1024 threads = 16 waves
// (4/SIMD, pinned), BB=16 batch rows.
//  waves 0-7  "A" (recurrence): wave w owns vv=w. Per step: read preG(t) from
//      s_pre ring (2x ds_read_b128) + h frags, 4 MFMA (h*W_hh), in-register
//      gates (parity interleave + lane-pair shfl, proven R4-R7), packed h
//      write. Serial path ~500 cy, nothing else on it.
//  waves 8-15 "B" (GEMM producer): wave 8+s owns vv=s. Per step: issue one
//      global_load_lds dwordx4 staging emb(t+3) chunk vv (TAB path; bf16
//      table, per-lane gather, linear LDS dest == fragment layout), then
//      preG(t+1) = bias + emb(t+1)*W_ih (8 ds_read_b128 + 16 MFMA, W_ih
//      register-resident) -> s_pre ring. No serial dependence on recurrence.
// Fragment LDS layout (zero-conflict, R5-proven): chunk (kc,lane) at
//   kc*1024B + lane*16B holds A[m=lane&15][k=kc*32+(lane>>4)*8+jj].
// One barrier per step.
// ---------------------------------------------------------------------------
template <int TAB>
__global__ __attribute__((amdgpu_flat_work_group_size(THREADS, THREADS),
                          amdgpu_waves_per_eu(4, 4)))
void lstm_split(const int* __restrict__ x,
                const float* __restrict__ embf,
                const short* __restrict__ embb,
                const short* __restrict__ wih_frag,
                const short* __restrict__ whh_g,
                const float* __restrict__ bias_f,
                float* __restrict__ out) {
    __shared__ __align__(16) short s_ef[4][4096];        // 4-ring emb, 8 KB each
    __shared__ __align__(16) float s_pre[2][8][2][256];  // 2-ring preG, 32 KB
    __shared__ __align__(16) short s_hf[2][1024];        // 2-ring h, 4 KB
    __shared__ int s_idx[1024];                          // [t][m]

    const int tid  = threadIdx.x;
    const int lane = tid & 63;
    const int wave = tid >> 6;
    const int r0   = blockIdx.x * 16;

    s_idx[(tid & 63) * 16 + (tid >> 6)] = x[(r0 + (tid >> 6)) * T_ + (tid & 63)];
    ((int*)s_hf)[tid] = 0;

    const int p   = lane & 1;
    const int c4  = lane >> 4;
    const int u   = (lane & 15) >> 1;
    const int m16 = lane & 15;
    const int m0  = c4 * 4 + p * 2;
    const float scl2 = p ? 1.0f : 2.0f;
    const float offB = p ? 0.0f : -1.0f;

    // A-wave state
    bf16x8 qA0, qA1, qB0, qB1;
    int hw_s = 0;
    // B-wave state
    bf16x8 wA[8], wB[8];
    float bA = 0.f, bB = 0.f;
    int vv;

    if (wave < 8) {
        vv = wave;
        const int gA = p * 64 + vv * 8 + u;
        const short* qp = whh_g + gA * 64 + c4 * 8;
        qA0 = *(const bf16x8*)(qp);
        qA1 = *(const bf16x8*)(qp + 32);
        qB0 = *(const bf16x8*)(qp + 8192);
        qB1 = *(const bf16x8*)(qp + 8192 + 32);
        hw_s = (vv >> 2) * 512 + (vv & 3) * 128
             + ((u & 1) ? (m0 + 1) * 8 + (u - 1) : m0 * 8 + u);
    } else {
        vv = wave - 8;
        const short* wp = wih_frag + vv * 8192 + lane * 8;
        #pragma unroll
        for (int kc = 0; kc < 8; ++kc) {
            wA[kc] = *(const bf16x8*)(wp + kc * 512);
            wB[kc] = *(const bf16x8*)(wp + 4096 + kc * 512);
        }
        const int gA = p * 64 + vv * 8 + u;
        bA = bias_f[gA];
        bB = bias_f[gA + 128];
    }

    __syncthreads();   // s_idx, h=0 visible

    // ---- prologue stage: emb(0)->buf0 (waves 0-7), emb(1)->buf1 (waves 8-15)
    {
        const int stt = wave >> 3;   // 0 or 1
        const int chk = wave & 7;
        const int tok = s_idx[stt * 16 + m16];
        if (TAB) {
            gld16(embb + (size_t)tok * E_ + chk * 32 + c4 * 8,
                  &s_ef[stt][chk * 512]);
        } else {
            const float* pr = embf + (size_t)tok * E_ + chk * 32 + c4 * 8;
            float4 f0 = *(const float4*)pr;
            float4 f1 = *(const float4*)(pr + 4);
            u32x4 w;
            w[0] = cvt_pk_bf16(f0.x, f0.y);
            w[1] = cvt_pk_bf16(f0.z, f0.w);
            w[2] = cvt_pk_bf16(f1.x, f1.y);
            w[3] = cvt_pk_bf16(f1.z, f1.w);
            *(u32x4*)(&s_ef[stt][chk * 512] + lane * 8) = w;
        }
    }
    __syncthreads();   // buf0, buf1 staged

    // ---- B prologue: stage emb(2), preG(0) -> s_pre ring 0 ----
    if (wave >= 8) {
        float4 f0, f1;
        if (TAB) {
            int tok2 = s_idx[2 * 16 + m16];
            gld16(embb + (size_t)tok2 * E_ + vv * 32 + c4 * 8, &s_ef[2][vv * 512]);
        } else {
            int tok2 = s_idx[2 * 16 + m16];
            const float* pr = embf + (size_t)tok2 * E_ + vv * 32 + c4 * 8;
            f0 = *(const float4*)pr;
            f1 = *(const float4*)(pr + 4);
        }
        f32x4 pA = {bA, bA, bA, bA};
        f32x4 pB = {bB, bB, bB, bB};
        const short* eb = &s_ef[0][0] + lane * 8;
        #pragma unroll
        for (int kc = 0; kc < 8; ++kc) {
            bf16x8 av = *(const bf16x8*)(eb + kc * 512);
            pA = __builtin_amdgcn_mfma_f32_16x16x32_bf16(av, wA[kc], pA, 0, 0, 0);
            pB = __builtin_amdgcn_mfma_f32_16x16x32_bf16(av, wB[kc], pB, 0, 0, 0);
        }
        *(f32x4*)&s_pre[0][vv][0][lane * 4] = pA;
        *(f32x4*)&s_pre[0][vv][1][lane * 4] = pB;
        if (!TAB) {
            u32x4 w;
            w[0] = cvt_pk_bf16(f0.x, f0.y);
            w[1] = cvt_pk_bf16(f0.z, f0.w);
            w[2] = cvt_pk_bf16(f1.x, f1.y);
            w[3] = cvt_pk_bf16(f1.z, f1.w);
            *(u32x4*)(&s_ef[2][vv * 512] + lane * 8) = w;
        }
    }
    __syncthreads();   // preG(0), buf2 ready

    float c0 = 0.f, c1 = 0.f, h0v = 0.f, h1v = 0.f;

    #pragma unroll 4
    for (int t = 0; t < T_; ++t) {
        if (wave < 8) {
            // ---- A: G(t) = preG(t) + h(t-1)*Whh ; gates ----
            f32x4 pA = *(const f32x4*)&s_pre[t & 1][vv][0][lane * 4];
            f32x4 pB = *(const f32x4*)&s_pre[t & 1][vv][1][lane * 4];
            const short* hb = &s_hf[t & 1][0] + lane * 8;
            bf16x8 hv0 = *(const bf16x8*)(hb);
            bf16x8 hv1 = *(const bf16x8*)(hb + 512);
            pA = __builtin_amdgcn_mfma_f32_16x16x32_bf16(hv0, qA0, pA, 0, 0, 0);
            pA = __builtin_amdgcn_mfma_f32_16x16x32_bf16(hv1, qA1, pA, 0, 0, 0);
            pB = __builtin_amdgcn_mfma_f32_16x16x32_bf16(hv0, qB0, pB, 0, 0, 0);
            pB = __builtin_amdgcn_mfma_f32_16x16x32_bf16(hv1, qB1, pB, 0, 0, 0);

            float sA[4], Bv[4];
            #pragma unroll
            for (int q = 0; q < 4; ++q) {
                sA[q] = sigm(pA[q]);                          // sigm(i) | sigm(f)
                Bv[q] = sigm(scl2 * pB[q]) * scl2 + offB;     // tanh(g) | sigm(o)
            }
            float s1 = p ? sA[0] : sA[2] * Bv[2];
            float r1 = __shfl_xor(s1, 1);
            float s2 = p ? sA[1] : sA[3] * Bv[3];
            float r2 = __shfl_xor(s2, 1);
            float r3 = __shfl_xor(Bv[0], 1);
            float r4 = __shfl_xor(Bv[1], 1);
            float fc0 = p ? sA[2] : r1;
            float ic0 = p ? r1 : sA[0] * Bv[0];
            float oc0 = p ? Bv[2] : r3;
            float fc1 = p ? sA[3] : r2;
            float ic1 = p ? r2 : sA[1] * Bv[1];
            float oc1 = p ? Bv[3] : r4;
            c0 = fc0 * c0 + ic0;
            c1 = fc1 * c1 + ic1;
            h0v = oc0 * tanh_(c0);
            h1v = oc1 * tanh_(c1);

            float snd = (u & 1) ? h0v : h1v;
            float rcv = __shfl_xor(snd, 2);
            unsigned hw = (u & 1) ? cvt_pk_bf16(rcv, h1v) : cvt_pk_bf16(h0v, rcv);
            *(unsigned*)(&s_hf[(t + 1) & 1][0] + hw_s) = hw;
        } else {
            // ---- B: stage emb(t+3); preG(t+1) -> s_pre ring (t+1)&1 ----
            float4 f0, f1;
            if (TAB) {
                if (t + 3 < T_) {
                    int tok = s_idx[(t + 3) * 16 + m16];
                    gld16(embb + (size_t)tok * E_ + vv * 32 + c4 * 8,
                          &s_ef[(t + 3) & 3][vv * 512]);
                }
            } else {
                if (t + 2 < T_) {
                    int tok = s_idx[(t + 2) * 16 + m16];
                    const float* pr = embf + (size_t)tok * E_ + vv * 32 + c4 * 8;
                    f0 = *(const float4*)pr;
                    f1 = *(const float4*)(pr + 4);
                }
            }
            if (t < T_ - 1) {
                f32x4 pA = {bA, bA, bA, bA};
                f32x4 pB = {bB, bB, bB, bB};
                const short* eb = &s_ef[(t + 1) & 3][0] + lane * 8;
                #pragma unroll
                for (int kc = 0; kc < 8; ++kc) {
                    bf16x8 av = *(const bf16x8*)(eb + kc * 512);
                    pA = __builtin_amdgcn_mfma_f32_16x16x32_bf16(av, wA[kc], pA, 0, 0, 0);
                    pB = __builtin_amdgcn_mfma_f32_16x16x32_bf16(av, wB[kc], pB, 0, 0, 0);
                }
                *(f32x4*)&s_pre[(t + 1) & 1][vv][0][lane * 4] = pA;
                *(f32x4*)&s_pre[(t + 1) & 1][vv][1][lane * 4] = pB;
            }
            if (!TAB) {
                if (t + 2 < T_) {
                    u32x4 w;
                    w[0] = cvt_pk_bf16(f0.x, f0.y);
                    w[1] = cvt_pk_bf16(f0.z, f0.w);
                    w[2] = cvt_pk_bf16(f1.x, f1.y);
                    w[3] = cvt_pk_bf16(f1.z, f1.w);
                    *(u32x4*)(&s_ef[(t + 2) & 3][vv * 512] + lane * 8) = w;
                }
            }
        }
        __syncthreads();
    }

    if (wave < 8) {
        const int j = vv * 8 + u;
        out[(r0 + m0) * H_ + j]     = h0v;
        out[(r0 + m0 + 1) * H_ + j] = h1v;
    }
}

// ---------------------------------------------------------------------------
extern "C" void kernel_launch(void* const* d_in, const int* in_sizes, int n_in,
                              void* d_out, int out_size, void* d_ws, size_t ws_size,
                              hipStream_t stream) {
    const int*   x         = (const int*)d_in[0];
    const float* emb_table = (const float*)d_in[1];
    const float* W_ih      = (const float*)d_in[2];
    const float* W_hh      = (const float*)d_in[3];
    const float* b_ih      = (const float*)d_in[4];
    const float* b_hh      = (const float*)d_in[5];
    float*       out       = (float*)d_out;

    short* wih_frag = (short*)d_ws;               // 65536 shorts (128 KB)
    short* whh_g    = wih_frag + 65536;           // 16384 shorts (32 KB)
    float* bias_f   = (float*)(whh_g + 16384);    // 256 floats (1 KB)
    short* emb_bf   = (short*)(bias_f + 256);     // 8.192M shorts (16.4 MB)

    const size_t need = (size_t)(65536 + 16384) * 2 + 256 * 4
                      + (size_t)V_ * E_ * 2;      // = 16,548,864 bytes
    const int tab = (ws_size >= need) ? 1 : 0;

    prep_kernel<<<tab ? 512 : 64, 256, 0, stream>>>(
        W_ih, W_hh, b_ih, b_hh, emb_table,
        wih_frag, whh_g, bias_f,
        tab ? emb_bf : wih_frag, tab ? V_ * E_ : 0);

    if (tab) {
        lstm_split<1><<<B_ / 16, THREADS, 0, stream>>>(
            x, emb_table, emb_bf, wih_frag, whh_g, bias_f, out);
    } else {
        lstm_split<0><<<B_ / 16, THREADS, 0, stream>>>(
            x, emb_table, wih_frag, wih_frag, whh_g, bias_f, out);
    }
}